// Round 5
// baseline (198.898 us; speedup 1.0000x reference)
//
#include <hip/hip_runtime.h>
#include <hip/hip_bf16.h>
#include <math.h>
#include <string.h>

// BilateralNet round 4b: rotation-split blocks + LDS aliasing + fast converts.
// (round-4 resubmit: pk2's __builtin_bit_cast on __hip_bfloat162 was rejected
//  -- not trivially copyable; replaced with memcpy which folds to a no-op.)
// - grid 9600: one (tile, batch, mode, rotation) per block -> tail fill 94%.
// - red[] reduction buffer aliased into Xs (dead by then) -> LDS = 40960 B
//   exactly -> 4 blocks/CU (was 3).
// - packed bf16 converts (v_cvt_pk_bf16_f32) in all epilogues; __expf-based
//   bilateral. b6 folded into the bilateral kernel (par/12 + b6).

#define NN   160
#define NPIX 25600   // 160*160

typedef __attribute__((ext_vector_type(4))) float float4v;
typedef __attribute__((ext_vector_type(8))) unsigned short ushort8;
typedef __attribute__((ext_vector_type(2))) unsigned int uint2v;
typedef __attribute__((ext_vector_type(4))) unsigned int uint4v;
typedef __attribute__((ext_vector_type(8))) __bf16 bf16x8;

__device__ __forceinline__ int refp(int a) { return (a <= NN - 1) ? a : (2 * (NN - 1) - a); }

__device__ __forceinline__ unsigned short f2b(float f) {
    unsigned int x = __float_as_uint(f);
    return (unsigned short)((x + 0x7FFFu + ((x >> 16) & 1u)) >> 16);  // RNE bf16
}
__device__ __forceinline__ unsigned int pk2(float lo, float hi) {
    float2 f; f.x = lo; f.y = hi;
    __hip_bfloat162 h = __float22bfloat162_rn(f);   // v_cvt_pk_bf16_f32 on gfx950
    unsigned int u;
    memcpy(&u, &h, 4);
    return u;
}

// ---- weight pre-conversion: fp32 -> bf16 row-major into d_ws ----
// layout (ushort idx): [0,4096) w2 ; [4096,12288) w3 ; [12288,24576) w4 ;
//                      [24576,40960) w5 ; [40960,46080) w6 padded to 16x320
__global__ __launch_bounds__(256) void bnet_wconv_kernel(
    const float* __restrict__ w2, const float* __restrict__ w3,
    const float* __restrict__ w4, const float* __restrict__ w5,
    const float* __restrict__ w6, unsigned short* __restrict__ wb)
{
    const int t = blockIdx.x * 256 + threadIdx.x;  // 46080 threads exactly
    if (t < 4096)       wb[t] = f2b(w2[t]);
    else if (t < 12288) wb[t] = f2b(w3[t - 4096]);
    else if (t < 24576) wb[t] = f2b(w4[t - 12288]);
    else if (t < 40960) wb[t] = f2b(w5[t - 24576]);
    else {
        const int i = t - 40960;         // row*320+col, row<16
        wb[t] = (i < 4 * 320) ? f2b(w6[i]) : (unsigned short)0;
    }
}

// one dense layer: reads X[0..K), writes relu(W X + b) into X[K..K+64)
template <int NCH>  // K = NCH*32 input channels
__device__ __forceinline__ void dense_layer(const ushort8 (&A)[NCH], float4v biasv,
                                            unsigned short* Xs, int w, int lo16, int lq) {
    const int K = NCH * 32;
#pragma unroll
    for (int pp = 0; pp < 2; ++pp) {
        const int px0 = (pp * 2) * 16 + lo16;
        const int px1 = (pp * 2 + 1) * 16 + lo16;
        float4v acc0 = biasv, acc1 = biasv;
#pragma unroll
        for (int s = 0; s < NCH; ++s) {
            const int c8 = s * 4 + lq;
            const bf16x8 bf0 = __builtin_bit_cast(bf16x8, *(const ushort8*)&Xs[c8 * 512 + px0 * 8]);
            const bf16x8 bf1 = __builtin_bit_cast(bf16x8, *(const ushort8*)&Xs[c8 * 512 + px1 * 8]);
            const bf16x8 af  = __builtin_bit_cast(bf16x8, A[s]);
            acc0 = __builtin_amdgcn_mfma_f32_16x16x32_bf16(af, bf0, acc0, 0, 0, 0);
            acc1 = __builtin_amdgcn_mfma_f32_16x16x32_bf16(af, bf1, acc1, 0, 0, 0);
        }
        const int cb = K + w * 16 + lq * 4;
        uint2v o0, o1;
        o0[0] = pk2(fmaxf(acc0[0], 0.0f), fmaxf(acc0[1], 0.0f));
        o0[1] = pk2(fmaxf(acc0[2], 0.0f), fmaxf(acc0[3], 0.0f));
        o1[0] = pk2(fmaxf(acc1[0], 0.0f), fmaxf(acc1[1], 0.0f));
        o1[1] = pk2(fmaxf(acc1[2], 0.0f), fmaxf(acc1[3], 0.0f));
        *(uint2v*)&Xs[(cb >> 3) * 512 + px0 * 8 + (cb & 7)] = o0;
        *(uint2v*)&Xs[(cb >> 3) * 512 + px1 * 8 + (cb & 7)] = o1;
    }
    __syncthreads();
}

__global__ __launch_bounds__(256, 4) void bnet_mlp_kernel(
    const float* __restrict__ x,
    const float* __restrict__ wx, const float* __restrict__ bx,
    const float* __restrict__ wcs, const float* __restrict__ bcs,
    const float* __restrict__ wc, const float* __restrict__ bc,
    const unsigned short* __restrict__ wb,   // bf16 weights in d_ws
    const float* __restrict__ b2, const float* __restrict__ b3,
    const float* __restrict__ b4, const float* __restrict__ b5,
    float* __restrict__ par)  // par[ch][b][pix], ch-major; pre-zeroed
{
    __shared__ unsigned short Xs[20480];    // 40 chunks x 1024 B = 40 KB exactly
    float* red = (float*)Xs;                // [w][pt][lo16][r] = 4 KB, aliased (dead region)

    const int t = threadIdx.x;
    const int lane = t & 63;
    const int lo16 = lane & 15;
    const int lq = lane >> 4;
    const int w = __builtin_amdgcn_readfirstlane(t >> 6);  // wave id 0..3 = o-tile

    const int bid = blockIdx.x;          // 9600 = 400 tiles * 2 b * 3 modes * 4 rot
    const int tile = bid % 400;
    const int b = (bid / 400) & 1;
    const int mode = (bid / 800) % 3;    // 0='x', 1='s', 2='c'
    const int k = bid / 2400;            // rotation 0..3

    const float* xb = x + b * NPIX;
    const float* w1 = (mode == 0) ? wx : (mode == 1) ? wcs : wc;
    const float* b1 = (mode == 0) ? bx : (mode == 1) ? bcs : bc;
    int DY[4], DX[4];
    if (mode == 0)      { DY[0]=0; DY[1]=0; DY[2]=1; DY[3]=1;  DX[0]=0; DX[1]=1; DX[2]=0; DX[3]=1; }
    else if (mode == 1) { DY[0]=0; DY[1]=1; DY[2]=1; DY[3]=2;  DX[0]=0; DX[1]=1; DX[2]=2; DX[3]=1; }
    else                { DY[0]=0; DY[1]=0; DY[2]=2; DY[3]=2;  DX[0]=0; DX[1]=2; DX[2]=0; DX[3]=2; }

    // ---- stage this wave's A-fragments into registers (once per block) ----
    const int arow = w * 16 + lo16;
    ushort8 a2[2], a3[4], a4[6], a5[8], a6[3];
#pragma unroll
    for (int s = 0; s < 2; ++s) a2[s] = *(const ushort8*)&wb[arow * 64 + s * 32 + lq * 8];
#pragma unroll
    for (int s = 0; s < 4; ++s) a3[s] = *(const ushort8*)&wb[4096 + arow * 128 + s * 32 + lq * 8];
#pragma unroll
    for (int s = 0; s < 6; ++s) a4[s] = *(const ushort8*)&wb[12288 + arow * 192 + s * 32 + lq * 8];
#pragma unroll
    for (int s = 0; s < 8; ++s) a5[s] = *(const ushort8*)&wb[24576 + arow * 256 + s * 32 + lq * 8];
#pragma unroll
    for (int c = 0; c < 3; ++c) {
        const int ch = (3 * w + c) * 32;   // wave w covers w6 K-chunks 3w..3w+2
        if (ch < 320) {
            a6[c] = *(const ushort8*)&wb[40960 + lo16 * 320 + ch + lq * 8];
        } else {
            ushort8 z = {0, 0, 0, 0, 0, 0, 0, 0};
            a6[c] = z;                     // zero A -> zero contribution
        }
    }
    const float4v b2v = *(const float4v*)&b2[w * 16 + lq * 4];
    const float4v b3v = *(const float4v*)&b3[w * 16 + lq * 4];
    const float4v b4v = *(const float4v*)&b4[w * 16 + lq * 4];
    const float4v b5v = *(const float4v*)&b5[w * 16 + lq * 4];

    const int pix = tile * 64 + lane;
    const int pi = pix / NN;
    const int pj = pix - pi * NN;

    // ---- stage 1: 4-tap conv; thread owns ch w*16..+15 at px=lane ----
    float s4[4];
#pragma unroll
    for (int tt = 0; tt < 4; ++tt) {
        const int dy = DY[tt], dx = DX[tt];
        int r, c;
        if (k == 0)      { r = refp(pi + dy); c = refp(pj + dx); }
        else if (k == 1) { r = refp(pi + dx); c = (pj >= dy) ? (pj - dy) : (dy - pj); }
        else if (k == 2) { r = (pi >= dy) ? (pi - dy) : (dy - pi);
                           c = (pj >= dx) ? (pj - dx) : (dx - pj); }
        else             { r = (pi >= dx) ? (pi - dx) : (dx - pi); c = refp(pj + dy); }
        s4[tt] = xb[r * NN + c];
    }
    float co[16];
#pragma unroll
    for (int oo = 0; oo < 16; ++oo) {
        const int o = w * 16 + oo;
        float cacc = b1[o];
#pragma unroll
        for (int tt = 0; tt < 4; ++tt) cacc = fmaf(w1[o * 4 + tt], s4[tt], cacc);
        co[oo] = fmaxf(cacc, 0.0f);
    }
    uint4v pka, pkb;
#pragma unroll
    for (int q = 0; q < 4; ++q) {
        pka[q] = pk2(co[2 * q], co[2 * q + 1]);
        pkb[q] = pk2(co[8 + 2 * q], co[9 + 2 * q]);
    }
    *(uint4v*)&Xs[(w * 2) * 512 + lane * 8]     = pka;
    *(uint4v*)&Xs[(w * 2 + 1) * 512 + lane * 8] = pkb;
    __syncthreads();

    dense_layer<2>(a2, b2v, Xs, w, lo16, lq);
    dense_layer<4>(a3, b3v, Xs, w, lo16, lq);
    dense_layer<6>(a4, b4v, Xs, w, lo16, lq);
    dense_layer<8>(a5, b5v, Xs, w, lo16, lq);

    // ---- final layer partials: wave w covers K-chunks 3w..3w+2 ----
    float4v acc6[4];
#pragma unroll
    for (int pt = 0; pt < 4; ++pt) { float4v z = {0.f, 0.f, 0.f, 0.f}; acc6[pt] = z; }
#pragma unroll
    for (int pt = 0; pt < 4; ++pt) {
        const int px = pt * 16 + lo16;
#pragma unroll
        for (int c = 0; c < 3; ++c) {
            int chb = (3 * w + c) * 32;
            chb = (chb < 288) ? chb : 288;   // clamp: A is zero there anyway
            const int c8 = (chb >> 3) + lq;
            const bf16x8 bf = __builtin_bit_cast(
                bf16x8, *(const ushort8*)&Xs[c8 * 512 + px * 8]);
            const bf16x8 af = __builtin_bit_cast(bf16x8, a6[c]);
            acc6[pt] = __builtin_amdgcn_mfma_f32_16x16x32_bf16(af, bf, acc6[pt], 0, 0, 0);
        }
    }
    __syncthreads();   // all w6 reads of Xs complete before red aliases it

    // ---- reduce w6 partials across waves; rows 0..3 live at lq==0 ----
    if (lq == 0) {
#pragma unroll
        for (int pt = 0; pt < 4; ++pt)
            *(float4v*)&red[(((w * 4) + pt) * 16 + lo16) * 4] = acc6[pt];
    }
    __syncthreads();
    if (w == 0) {
        // 64 lanes of wave 0: p-tile = lq, pixel-in-tile = lo16
        float4v sv;
#pragma unroll
        for (int r = 0; r < 4; ++r)
            sv[r] = red[(((0 * 4) + lq) * 16 + lo16) * 4 + r]
                  + red[(((1 * 4) + lq) * 16 + lo16) * 4 + r]
                  + red[(((2 * 4) + lq) * 16 + lo16) * 4 + r]
                  + red[(((3 * 4) + lq) * 16 + lo16) * 4 + r];
        const int pixg = tile * 64 + lq * 16 + lo16;
#pragma unroll
        for (int r = 0; r < 4; ++r)
            atomicAdd(&par[(r * 2 + b) * NPIX + pixg], sv[r]);   // b6 folded into kernel 2
    }
}

__global__ __launch_bounds__(256) void bnet_bilateral_kernel(
    const float* __restrict__ x, const float* __restrict__ b6,
    float* __restrict__ out)
{
    const int tid = blockIdx.x * 256 + threadIdx.x;  // 51200 threads exactly
    const int b = tid / NPIX;
    const int pix = tid - b * NPIX;
    const int pi = pix / NN;
    const int pj = pix - pi * NN;

    float* par = out + 2 * NPIX;
    const float inv12 = 1.0f / 12.0f;
    const float p0 = par[(0 + b) * NPIX + pix] * inv12 + b6[0];
    const float p1 = par[(2 + b) * NPIX + pix] * inv12 + b6[1];
    const float p2 = par[(4 + b) * NPIX + pix] * inv12 + b6[2];
    const float p3 = par[(6 + b) * NPIX + pix] * inv12 + b6[3];

    float sigx = 1.0f / (1.0f + __expf(-p0)) + 1e-6f;
    sigx = fminf(fmaxf(sigx, 0.0f), 1.0f);
    float sigy = 1.0f / (1.0f + __expf(-p1)) + 1e-6f;
    sigy = fminf(fmaxf(sigy, 0.0f), 1.0f);
    float t2 = __expf(2.0f * fminf(fmaxf(p2, -15.0f), 15.0f));
    float th = (t2 - 1.0f) / (t2 + 1.0f);
    th = fminf(fmaxf(th, -1.0f), 1.0f);
    float t3 = __expf(2.0f * fminf(fmaxf(p3, -15.0f), 15.0f));
    float sigr = (t3 - 1.0f) / (t3 + 1.0f) + 1e-6f;
    sigr = fminf(fmaxf(sigr, -1.0f), 1.0f);

    par[(0 + b) * NPIX + pix] = sigx;
    par[(2 + b) * NPIX + pix] = sigy;
    par[(4 + b) * NPIX + pix] = th;
    par[(6 + b) * NPIX + pix] = sigr;

    const float sx = sigx * 20.0f;
    const float sy = sigy * 20.0f;
    const float sr = sigr * 10.0f + 10.0f;

    const float* xb = x + b * NPIX;
    float patch[5][5];
#pragma unroll
    for (int ky = 0; ky < 5; ++ky) {
#pragma unroll
        for (int kx = 0; kx < 5; ++kx) {
            const int r = pi + ky - 2, c = pj + kx - 2;
            patch[ky][kx] = (r >= 0 && r < NN && c >= 0 && c < NN) ? xb[r * NN + c] : 0.0f;
        }
    }

    const float inv2sr2 = 1.0f / (2.0f * sr * sr);
    float num = 0.0f, den = 0.0f;
#pragma unroll
    for (int ky = 0; ky < 5; ++ky) {
#pragma unroll
        for (int kx = 0; kx < 5; ++kx) {
            const float v = patch[ky][kx];
            const float dxv = fabsf(patch[2][kx] - v);
            const float dyv = fabsf(patch[ky][2] - v);
            const float a = sx * dxv;
            const float bb = sy * dyv;
            const float sq = (float)((ky - 2) * (ky - 2) + (kx - 2) * (kx - 2));
            const float kern = __expf(-sq * inv2sr2 - 0.5f * (a * a - 2.0f * th * a * bb + bb * bb));
            den += kern;
            num = fmaf(kern, v, num);
        }
    }
    out[tid] = num / den;
}

extern "C" void kernel_launch(void* const* d_in, const int* in_sizes, int n_in,
                              void* d_out, int out_size, void* d_ws, size_t ws_size,
                              hipStream_t stream) {
    const float* x   = (const float*)d_in[0];
    const float* wx  = (const float*)d_in[1];
    const float* bx  = (const float*)d_in[2];
    const float* wc  = (const float*)d_in[3];
    const float* bc  = (const float*)d_in[4];
    const float* wcs = (const float*)d_in[5];
    const float* bcs = (const float*)d_in[6];
    const float* w2  = (const float*)d_in[7];
    const float* b2  = (const float*)d_in[8];
    const float* w3  = (const float*)d_in[9];
    const float* b3  = (const float*)d_in[10];
    const float* w4  = (const float*)d_in[11];
    const float* b4  = (const float*)d_in[12];
    const float* w5  = (const float*)d_in[13];
    const float* b5  = (const float*)d_in[14];
    const float* w6  = (const float*)d_in[15];
    const float* b6  = (const float*)d_in[16];
    float* out = (float*)d_out;
    unsigned short* wb = (unsigned short*)d_ws;  // 46080 ushorts = 92160 B

    // zero the par accumulator region (d_out tail, re-poisoned each launch)
    (void)hipMemsetAsync(out + 2 * NPIX, 0, 8 * NPIX * sizeof(float), stream);

    hipLaunchKernelGGL(bnet_wconv_kernel, dim3(180), dim3(256), 0, stream,
                       w2, w3, w4, w5, w6, wb);

    hipLaunchKernelGGL(bnet_mlp_kernel, dim3(9600), dim3(256), 0, stream,
                       x, wx, bx, wcs, bcs, wc, bc,
                       wb, b2, b3, b4, b5,
                       out + 2 * NPIX);

    hipLaunchKernelGGL(bnet_bilateral_kernel, dim3(200), dim3(256), 0, stream,
                       x, b6, out);
}

// Round 6
// 182.919 us; speedup vs baseline: 1.0874x; 1.0874x over previous
//
#include <hip/hip_runtime.h>
#include <hip/hip_bf16.h>
#include <math.h>
#include <string.h>

// BilateralNet round 6: persistent-chunk blocks + register-resident weights.
// Round-5 lesson: VGPR_Count=64 proved the compiler sank the weight loads into
// every dense layer (launch_bounds cap 128 too tight), and the rotation split
// de-amortized staging 8x (9600 blocks x 90 KB L2 reads).
// Fix: grid=768 (exactly 3 blocks/CU, no tail), each block loops over 12-13
// contiguous (tile,b,mode,rot) items; weights converted fp32->bf16 INLINE once
// per block (wconv dispatch + d_ws removed); __launch_bounds__(256,3) gives
// ~170 VGPRs so the staged fragments stay register-resident across the loop.

#define NN   160
#define NPIX 25600   // 160*160

typedef __attribute__((ext_vector_type(4))) float float4v;
typedef __attribute__((ext_vector_type(8))) unsigned short ushort8;
typedef __attribute__((ext_vector_type(2))) unsigned int uint2v;
typedef __attribute__((ext_vector_type(4))) unsigned int uint4v;
typedef __attribute__((ext_vector_type(8))) __bf16 bf16x8;

__device__ __forceinline__ int refp(int a) { return (a <= NN - 1) ? a : (2 * (NN - 1) - a); }

__device__ __forceinline__ unsigned int pk2(float lo, float hi) {
    float2 f; f.x = lo; f.y = hi;
    __hip_bfloat162 h = __float22bfloat162_rn(f);   // v_cvt_pk_bf16_f32
    unsigned int u;
    memcpy(&u, &h, 4);
    return u;
}
__device__ __forceinline__ ushort8 cvt8(const float* __restrict__ p) {
    const float4v f0 = *(const float4v*)p;
    const float4v f1 = *(const float4v*)(p + 4);
    uint4v u;
    u[0] = pk2(f0[0], f0[1]); u[1] = pk2(f0[2], f0[3]);
    u[2] = pk2(f1[0], f1[1]); u[3] = pk2(f1[2], f1[3]);
    return __builtin_bit_cast(ushort8, u);
}

// one dense layer: reads X[0..K), writes relu(W X + b) into X[K..K+64)
template <int NCH>  // K = NCH*32 input channels
__device__ __forceinline__ void dense_layer(const ushort8 (&A)[NCH], float4v biasv,
                                            unsigned short* Xs, int w, int lo16, int lq) {
    const int K = NCH * 32;
#pragma unroll
    for (int pp = 0; pp < 2; ++pp) {
        const int px0 = (pp * 2) * 16 + lo16;
        const int px1 = (pp * 2 + 1) * 16 + lo16;
        float4v acc0 = biasv, acc1 = biasv;
#pragma unroll
        for (int s = 0; s < NCH; ++s) {
            const int c8 = s * 4 + lq;
            const bf16x8 bf0 = __builtin_bit_cast(bf16x8, *(const ushort8*)&Xs[c8 * 512 + px0 * 8]);
            const bf16x8 bf1 = __builtin_bit_cast(bf16x8, *(const ushort8*)&Xs[c8 * 512 + px1 * 8]);
            const bf16x8 af  = __builtin_bit_cast(bf16x8, A[s]);
            acc0 = __builtin_amdgcn_mfma_f32_16x16x32_bf16(af, bf0, acc0, 0, 0, 0);
            acc1 = __builtin_amdgcn_mfma_f32_16x16x32_bf16(af, bf1, acc1, 0, 0, 0);
        }
        const int cb = K + w * 16 + lq * 4;
        uint2v o0, o1;
        o0[0] = pk2(fmaxf(acc0[0], 0.0f), fmaxf(acc0[1], 0.0f));
        o0[1] = pk2(fmaxf(acc0[2], 0.0f), fmaxf(acc0[3], 0.0f));
        o1[0] = pk2(fmaxf(acc1[0], 0.0f), fmaxf(acc1[1], 0.0f));
        o1[1] = pk2(fmaxf(acc1[2], 0.0f), fmaxf(acc1[3], 0.0f));
        *(uint2v*)&Xs[(cb >> 3) * 512 + px0 * 8 + (cb & 7)] = o0;
        *(uint2v*)&Xs[(cb >> 3) * 512 + px1 * 8 + (cb & 7)] = o1;
    }
    __syncthreads();
}

__global__ __launch_bounds__(256, 3) void bnet_mlp_kernel(
    const float* __restrict__ x,
    const float* __restrict__ wx, const float* __restrict__ bx,
    const float* __restrict__ wcs, const float* __restrict__ bcs,
    const float* __restrict__ wc, const float* __restrict__ bc,
    const float* __restrict__ w2, const float* __restrict__ b2,
    const float* __restrict__ w3, const float* __restrict__ b3,
    const float* __restrict__ w4, const float* __restrict__ b4,
    const float* __restrict__ w5, const float* __restrict__ b5,
    const float* __restrict__ w6,
    float* __restrict__ par)  // par[ch][b][pix], ch-major; pre-zeroed
{
    __shared__ unsigned short Xs[20480];    // 40 chunks x 1024 B = 40 KB exactly
    float* red = (float*)Xs;                // 4 KB aliased into chunks 0-3 (dead region)

    const int t = threadIdx.x;
    const int lane = t & 63;
    const int lo16 = lane & 15;
    const int lq = lane >> 4;
    const int w = __builtin_amdgcn_readfirstlane(t >> 6);  // wave id 0..3 = o-tile

    // ---- stage this wave's A-fragments ONCE per block (fp32 -> bf16 inline) ----
    const int arow = w * 16 + lo16;
    ushort8 a2[2], a3[4], a4[6], a5[8], a6[3];
#pragma unroll
    for (int s = 0; s < 2; ++s) a2[s] = cvt8(&w2[arow * 64 + s * 32 + lq * 8]);
#pragma unroll
    for (int s = 0; s < 4; ++s) a3[s] = cvt8(&w3[arow * 128 + s * 32 + lq * 8]);
#pragma unroll
    for (int s = 0; s < 6; ++s) a4[s] = cvt8(&w4[arow * 192 + s * 32 + lq * 8]);
#pragma unroll
    for (int s = 0; s < 8; ++s) a5[s] = cvt8(&w5[arow * 256 + s * 32 + lq * 8]);
#pragma unroll
    for (int c = 0; c < 3; ++c) {
        // w6 is 4x320; padded to 16 rows. wave w covers K-chunks 3w..3w+2.
        const int ch = (3 * w + c) * 32;
        if (ch < 320 && lo16 < 4) {
            a6[c] = cvt8(&w6[lo16 * 320 + ch + lq * 8]);
        } else {
            ushort8 z = {0, 0, 0, 0, 0, 0, 0, 0};
            a6[c] = z;
        }
    }
    const float4v b2v = *(const float4v*)&b2[w * 16 + lq * 4];
    const float4v b3v = *(const float4v*)&b3[w * 16 + lq * 4];
    const float4v b4v = *(const float4v*)&b4[w * 16 + lq * 4];
    const float4v b5v = *(const float4v*)&b5[w * 16 + lq * 4];

    // ---- item chunk: 9600 items over 768 blocks -> 384 blocks x13 + 384 x12 ----
    const int bid = blockIdx.x;
    const int nit = 12 + (bid < 384 ? 1 : 0);
    const int g0  = (bid < 384) ? bid * 13 : bid * 12 + 384;

    for (int it = 0; it < nit; ++it) {
        const int g = g0 + it;            // g = (tile*2+b)*12 + (mode*4+k)
        const int v = g % 12;
        const int tb = g / 12;
        const int tile = tb >> 1;
        const int b = tb & 1;
        const int mode = v >> 2;          // 0='x', 1='s', 2='c'
        const int k = v & 3;              // rotation

        const float* xb = x + b * NPIX;
        const float* w1 = (mode == 0) ? wx : (mode == 1) ? wcs : wc;
        const float* b1 = (mode == 0) ? bx : (mode == 1) ? bcs : bc;
        int DY[4], DX[4];
        if (mode == 0)      { DY[0]=0; DY[1]=0; DY[2]=1; DY[3]=1;  DX[0]=0; DX[1]=1; DX[2]=0; DX[3]=1; }
        else if (mode == 1) { DY[0]=0; DY[1]=1; DY[2]=1; DY[3]=2;  DX[0]=0; DX[1]=1; DX[2]=2; DX[3]=1; }
        else                { DY[0]=0; DY[1]=0; DY[2]=2; DY[3]=2;  DX[0]=0; DX[1]=2; DX[2]=0; DX[3]=2; }

        const int pix = tile * 64 + lane;
        const int pi = pix / NN;
        const int pj = pix - pi * NN;

        __syncthreads();  // protect Xs chunks 0-7 (incl. red alias) vs prior item

        // ---- stage 1: 4-tap conv; thread owns ch w*16..+15 at px=lane ----
        float s4[4];
#pragma unroll
        for (int tt = 0; tt < 4; ++tt) {
            const int dy = DY[tt], dx = DX[tt];
            int r, c;
            if (k == 0)      { r = refp(pi + dy); c = refp(pj + dx); }
            else if (k == 1) { r = refp(pi + dx); c = (pj >= dy) ? (pj - dy) : (dy - pj); }
            else if (k == 2) { r = (pi >= dy) ? (pi - dy) : (dy - pi);
                               c = (pj >= dx) ? (pj - dx) : (dx - pj); }
            else             { r = (pi >= dx) ? (pi - dx) : (dx - pi); c = refp(pj + dy); }
            s4[tt] = xb[r * NN + c];
        }
        float co[16];
#pragma unroll
        for (int oo = 0; oo < 16; ++oo) {
            const int o = w * 16 + oo;
            float cacc = b1[o];
#pragma unroll
            for (int tt = 0; tt < 4; ++tt) cacc = fmaf(w1[o * 4 + tt], s4[tt], cacc);
            co[oo] = fmaxf(cacc, 0.0f);
        }
        uint4v pka, pkb;
#pragma unroll
        for (int q = 0; q < 4; ++q) {
            pka[q] = pk2(co[2 * q], co[2 * q + 1]);
            pkb[q] = pk2(co[8 + 2 * q], co[9 + 2 * q]);
        }
        *(uint4v*)&Xs[(w * 2) * 512 + lane * 8]     = pka;
        *(uint4v*)&Xs[(w * 2 + 1) * 512 + lane * 8] = pkb;
        __syncthreads();

        dense_layer<2>(a2, b2v, Xs, w, lo16, lq);
        dense_layer<4>(a3, b3v, Xs, w, lo16, lq);
        dense_layer<6>(a4, b4v, Xs, w, lo16, lq);
        dense_layer<8>(a5, b5v, Xs, w, lo16, lq);

        // ---- final layer partials: wave w covers K-chunks 3w..3w+2 ----
        float4v acc6[4];
#pragma unroll
        for (int pt = 0; pt < 4; ++pt) { float4v z = {0.f, 0.f, 0.f, 0.f}; acc6[pt] = z; }
#pragma unroll
        for (int pt = 0; pt < 4; ++pt) {
            const int px = pt * 16 + lo16;
#pragma unroll
            for (int c = 0; c < 3; ++c) {
                int chb = (3 * w + c) * 32;
                chb = (chb < 288) ? chb : 288;   // clamp: A is zero there anyway
                const int c8 = (chb >> 3) + lq;
                const bf16x8 bf = __builtin_bit_cast(
                    bf16x8, *(const ushort8*)&Xs[c8 * 512 + px * 8]);
                const bf16x8 af = __builtin_bit_cast(bf16x8, a6[c]);
                acc6[pt] = __builtin_amdgcn_mfma_f32_16x16x32_bf16(af, bf, acc6[pt], 0, 0, 0);
            }
        }
        __syncthreads();   // all w6 reads of Xs complete before red aliases it

        // ---- reduce w6 partials across waves; rows 0..3 live at lq==0 ----
        if (lq == 0) {
#pragma unroll
            for (int pt = 0; pt < 4; ++pt)
                *(float4v*)&red[(((w * 4) + pt) * 16 + lo16) * 4] = acc6[pt];
        }
        __syncthreads();
        if (w == 0) {
            // 64 lanes of wave 0: p-tile = lq, pixel-in-tile = lo16
            float4v sv;
#pragma unroll
            for (int r = 0; r < 4; ++r)
                sv[r] = red[(((0 * 4) + lq) * 16 + lo16) * 4 + r]
                      + red[(((1 * 4) + lq) * 16 + lo16) * 4 + r]
                      + red[(((2 * 4) + lq) * 16 + lo16) * 4 + r]
                      + red[(((3 * 4) + lq) * 16 + lo16) * 4 + r];
            const int pixg = tile * 64 + lq * 16 + lo16;
#pragma unroll
            for (int r = 0; r < 4; ++r)
                atomicAdd(&par[(r * 2 + b) * NPIX + pixg], sv[r]);  // b6 folded into kernel 2
        }
        // loop-top __syncthreads() protects red/Xs reuse across items
    }
}

__global__ __launch_bounds__(256) void bnet_bilateral_kernel(
    const float* __restrict__ x, const float* __restrict__ b6,
    float* __restrict__ out)
{
    const int tid = blockIdx.x * 256 + threadIdx.x;  // 51200 threads exactly
    const int b = tid / NPIX;
    const int pix = tid - b * NPIX;
    const int pi = pix / NN;
    const int pj = pix - pi * NN;

    float* par = out + 2 * NPIX;
    const float inv12 = 1.0f / 12.0f;
    const float p0 = par[(0 + b) * NPIX + pix] * inv12 + b6[0];
    const float p1 = par[(2 + b) * NPIX + pix] * inv12 + b6[1];
    const float p2 = par[(4 + b) * NPIX + pix] * inv12 + b6[2];
    const float p3 = par[(6 + b) * NPIX + pix] * inv12 + b6[3];

    float sigx = 1.0f / (1.0f + __expf(-p0)) + 1e-6f;
    sigx = fminf(fmaxf(sigx, 0.0f), 1.0f);
    float sigy = 1.0f / (1.0f + __expf(-p1)) + 1e-6f;
    sigy = fminf(fmaxf(sigy, 0.0f), 1.0f);
    float t2 = __expf(2.0f * fminf(fmaxf(p2, -15.0f), 15.0f));
    float th = (t2 - 1.0f) / (t2 + 1.0f);
    th = fminf(fmaxf(th, -1.0f), 1.0f);
    float t3 = __expf(2.0f * fminf(fmaxf(p3, -15.0f), 15.0f));
    float sigr = (t3 - 1.0f) / (t3 + 1.0f) + 1e-6f;
    sigr = fminf(fmaxf(sigr, -1.0f), 1.0f);

    par[(0 + b) * NPIX + pix] = sigx;
    par[(2 + b) * NPIX + pix] = sigy;
    par[(4 + b) * NPIX + pix] = th;
    par[(6 + b) * NPIX + pix] = sigr;

    const float sx = sigx * 20.0f;
    const float sy = sigy * 20.0f;
    const float sr = sigr * 10.0f + 10.0f;

    const float* xb = x + b * NPIX;
    float patch[5][5];
#pragma unroll
    for (int ky = 0; ky < 5; ++ky) {
#pragma unroll
        for (int kx = 0; kx < 5; ++kx) {
            const int r = pi + ky - 2, c = pj + kx - 2;
            patch[ky][kx] = (r >= 0 && r < NN && c >= 0 && c < NN) ? xb[r * NN + c] : 0.0f;
        }
    }

    const float inv2sr2 = 1.0f / (2.0f * sr * sr);
    float num = 0.0f, den = 0.0f;
#pragma unroll
    for (int ky = 0; ky < 5; ++ky) {
#pragma unroll
        for (int kx = 0; kx < 5; ++kx) {
            const float v = patch[ky][kx];
            const float dxv = fabsf(patch[2][kx] - v);
            const float dyv = fabsf(patch[ky][2] - v);
            const float a = sx * dxv;
            const float bb = sy * dyv;
            const float sq = (float)((ky - 2) * (ky - 2) + (kx - 2) * (kx - 2));
            const float kern = __expf(-sq * inv2sr2 - 0.5f * (a * a - 2.0f * th * a * bb + bb * bb));
            den += kern;
            num = fmaf(kern, v, num);
        }
    }
    out[tid] = num / den;
}

extern "C" void kernel_launch(void* const* d_in, const int* in_sizes, int n_in,
                              void* d_out, int out_size, void* d_ws, size_t ws_size,
                              hipStream_t stream) {
    const float* x   = (const float*)d_in[0];
    const float* wx  = (const float*)d_in[1];
    const float* bx  = (const float*)d_in[2];
    const float* wc  = (const float*)d_in[3];
    const float* bc  = (const float*)d_in[4];
    const float* wcs = (const float*)d_in[5];
    const float* bcs = (const float*)d_in[6];
    const float* w2  = (const float*)d_in[7];
    const float* b2  = (const float*)d_in[8];
    const float* w3  = (const float*)d_in[9];
    const float* b3  = (const float*)d_in[10];
    const float* w4  = (const float*)d_in[11];
    const float* b4  = (const float*)d_in[12];
    const float* w5  = (const float*)d_in[13];
    const float* b5  = (const float*)d_in[14];
    const float* w6  = (const float*)d_in[15];
    const float* b6  = (const float*)d_in[16];
    float* out = (float*)d_out;

    // zero the par accumulator region (d_out tail, re-poisoned each launch)
    (void)hipMemsetAsync(out + 2 * NPIX, 0, 8 * NPIX * sizeof(float), stream);

    hipLaunchKernelGGL(bnet_mlp_kernel, dim3(768), dim3(256), 0, stream,
                       x, wx, bx, wcs, bcs, wc, bc,
                       w2, b2, w3, b3, w4, b4, w5, b5, w6,
                       out + 2 * NPIX);

    hipLaunchKernelGGL(bnet_bilateral_kernel, dim3(200), dim3(256), 0, stream,
                       x, b6, out);
}